// Round 16
// baseline (208.573 us; speedup 1.0000x reference)
//
#include <hip/hip_runtime.h>
#include <hip/hip_bf16.h>
#include <math.h>

// Problem constants (B=2,S=2048 -> T=4096 tokens)
#define T_TOKENS 4096
#define D_DIM 768
#define F_DIM 3072
#define E_NUM 8

#define BM 128
#define BK 32
#define RBMAX 72                 // max padded 128-row blocks
#define NBU (F_DIM / 256)        // 12 N-blocks of 256 for up
#define NBD (D_DIM / 128)        // 6 N-blocks of 128 for down
#define UP_BLOCKS (NBU * RBMAX)  // 864
#define KHALF (F_DIM / 2)        // 1536: down split-K chunk
#define DN_BLOCKS (NBD * RBMAX * 2)  // 864 (rb outer x (nb,kc) inner)
#define GROWS (RBMAX * BM)       // 9216 padded rows

#define TILE_LDS (64 * 66)       // bf16 elems per wave-private transpose tile
#define TRT_WUP 4608             // 64x64 tiles in wup
#define TRT_TOT 9216             // + wdn

// fused prep: [0,2304) transpose (4 tiles/block) | [2304,2560) gate (16 tok/block)
#define PREP_TRANS (TRT_TOT / 4)     // 2304
#define PREP_GATE (T_TOKENS / 16)    // 256
#define PREP_TOTAL (PREP_TRANS + PREP_GATE)

typedef __attribute__((ext_vector_type(8))) short short8;
typedef __attribute__((ext_vector_type(4))) short short4v;
typedef __attribute__((ext_vector_type(4))) float float4v;
typedef unsigned short ushort_t;
typedef unsigned long long ull_t;

__device__ __forceinline__ ushort_t f2bf(float f) {
    union { float f; unsigned u; } v; v.f = f;
    unsigned r = v.u + 0x7fffu + ((v.u >> 16) & 1u);   // RNE
    return (ushort_t)(r >> 16);
}

__device__ __forceinline__ float bf2f(ushort_t u) {
    union { unsigned u; float f; } v; v.u = ((unsigned)u) << 16;
    return v.f;
}

__device__ __forceinline__ float gelu_fast(float v) {
    float u = v + 0.044715f * v * v * v;
    return v / (1.f + __expf(-1.5957691216f * u));
}

#define GLOAD_LDS16(gp, lp) __builtin_amdgcn_global_load_lds( \
    (const __attribute__((address_space(1))) void*)(gp),      \
    (__attribute__((address_space(3))) void*)(lp), 16, 0, 0)

// expert for padded 128-row block rb, plus total block count
__device__ __forceinline__ int rb_expert(const int* __restrict__ counts,
                                         int rb, int& total) {
    int e = 0, acc = 0;
#pragma unroll
    for (int ee = 0; ee < E_NUM; ++ee) {
        int nbe = (counts[ee] + BM - 1) / BM;
        if (rb >= acc && rb < acc + nbe) e = ee;
        acc += nbe;
    }
    total = acc;
    return e;
}

// ---------------------------------------------------------------- tile coords
__device__ __forceinline__ void tile_coords(int g, int R, int C,
                                            int& e, int& r0, int& c0) {
    int tpr = C / 64, tpc = R / 64;
    e = g / (tpr * tpc);
    int rem = g % (tpr * tpc);
    r0 = (rem / tpr) * 64;
    c0 = (rem % tpr) * 64;
}

// ------------------------------------------------- per-WAVE barrier-free transpose
__device__ __forceinline__ void wave_transpose64(const float* __restrict__ ip,
                                                 ushort_t* __restrict__ op,
                                                 int R, int C, int r0, int c0,
                                                 ushort_t* __restrict__ tl) {
    int l = threadIdx.x & 63;
    int lr = l >> 4;             // 0..3
    int lc4 = (l & 15) * 4;      // 0,4,...,60

    float4v v[16];
#pragma unroll
    for (int i = 0; i < 16; ++i)
        v[i] = *(const float4v*)&ip[(size_t)(r0 + 4 * i + lr) * C + c0 + lc4];
#pragma unroll
    for (int i = 0; i < 16; ++i) {
        short4v s = { (short)f2bf(v[i][0]), (short)f2bf(v[i][1]),
                      (short)f2bf(v[i][2]), (short)f2bf(v[i][3]) };
        *(short4v*)&tl[(4 * i + lr) * 66 + lc4] = s;
    }
    asm volatile("s_waitcnt lgkmcnt(0)" ::: "memory");
#pragma unroll
    for (int i = 0; i < 16; ++i) {
        int rr = 4 * i + lr;                     // output row (= orig col c0+rr)
        short4v s = { (short)tl[(lc4 + 0) * 66 + rr],
                      (short)tl[(lc4 + 1) * 66 + rr],
                      (short)tl[(lc4 + 2) * 66 + rr],
                      (short)tl[(lc4 + 3) * 66 + rr] };
        *(short4v*)&op[(size_t)(c0 + rr) * R + r0 + lc4] = s;
    }
}

// ---------------------------------------------------------------- fused prep
// uniform 33.8KB LDS for ALL blocks (r13 lesson: LDS size couples occupancy)
__global__ __launch_bounds__(256) void k_prep(const float* __restrict__ x,
                                              const float* __restrict__ gw,
                                              const float* __restrict__ wup,
                                              const float* __restrict__ wdn,
                                              int* __restrict__ counts,
                                              int* __restrict__ list,
                                              float* __restrict__ wsel,
                                              ushort_t* __restrict__ xb,
                                              ushort_t* __restrict__ wupT,
                                              ushort_t* __restrict__ wdnT) {
    __shared__ ushort_t ttile[4][TILE_LDS];
    __shared__ int hist[E_NUM];
    __shared__ int base[E_NUM];
    int bid = blockIdx.x;
    int wave = threadIdx.x >> 6, lane = threadIdx.x & 63;

    if (bid < PREP_TRANS) {
        // ---- transpose: 4 wave-private 64x64 tiles per block
        int g = bid * 4 + wave;               // 0..9215
        const float* in; ushort_t* outp; int R, C;
        if (g < TRT_WUP) { in = wup; outp = wupT; R = D_DIM; C = F_DIM; }
        else { g -= TRT_WUP; in = wdn; outp = wdnT; R = F_DIM; C = D_DIM; }
        int e, r0, c0;
        tile_coords(g, R, C, e, r0, c0);
        wave_transpose64(in + (size_t)e * R * C, outp + (size_t)e * R * C,
                         R, C, r0, c0, &ttile[wave][0]);
        return;
    }

    // ---- gate + x->bf16: 16 tokens/block (4 waves x 4 rounds), 8 atomics/block
    int tb = (bid - PREP_TRANS) * 16;
    if (threadIdx.x < E_NUM) hist[threadIdx.x] = 0;
    __syncthreads();

    int e1a[4], e2a[4], s1a[4], s2a[4];
#pragma unroll
    for (int r = 0; r < 4; ++r) {
        int t = tb + r * 4 + wave;
        float acc[E_NUM];
#pragma unroll
        for (int e = 0; e < E_NUM; ++e) acc[e] = 0.f;
        const float4v* xr4 = (const float4v*)(x + (size_t)t * D_DIM);
        ull_t* xbr = (ull_t*)(xb + (size_t)t * D_DIM);
#pragma unroll
        for (int i = 0; i < 3; ++i) {
            int j = lane + i * 64;               // float4 index within row
            float4v v = xr4[j];
            xbr[j] = (ull_t)f2bf(v[0]) | ((ull_t)f2bf(v[1]) << 16) |
                     ((ull_t)f2bf(v[2]) << 32) | ((ull_t)f2bf(v[3]) << 48);
            int d0 = 4 * j;
#pragma unroll
            for (int q = 0; q < 4; ++q) {
                const float* g = gw + (size_t)(d0 + q) * E_NUM;
#pragma unroll
                for (int e = 0; e < E_NUM; ++e) acc[e] += v[q] * g[e];
            }
        }
#pragma unroll
        for (int e = 0; e < E_NUM; ++e) {
#pragma unroll
            for (int s = 32; s >= 1; s >>= 1) acc[e] += __shfl_xor(acc[e], s);
        }
        if (lane == 0) {
            float mx = acc[0];
#pragma unroll
            for (int e = 1; e < E_NUM; ++e) mx = fmaxf(mx, acc[e]);
            float p[E_NUM], sum = 0.f;
#pragma unroll
            for (int e = 0; e < E_NUM; ++e) { p[e] = expf(acc[e] - mx); sum += p[e]; }
            float inv = 1.f / sum;
#pragma unroll
            for (int e = 0; e < E_NUM; ++e) p[e] *= inv;
            int e1 = 0;
#pragma unroll
            for (int e = 1; e < E_NUM; ++e) if (p[e] > p[e1]) e1 = e;
            int e2 = (e1 == 0) ? 1 : 0;
#pragma unroll
            for (int e = 0; e < E_NUM; ++e) if (e != e1 && p[e] > p[e2]) e2 = e;
            e1a[r] = e1; e2a[r] = e2;
            s1a[r] = atomicAdd(&hist[e1], 1);    // LDS atomic
            s2a[r] = atomicAdd(&hist[e2], 1);
            wsel[t * 2 + 0] = p[e1];
            wsel[t * 2 + 1] = p[e2];
        }
    }
    __syncthreads();
    if (threadIdx.x < E_NUM)
        base[threadIdx.x] = atomicAdd(&counts[threadIdx.x], hist[threadIdx.x]);
    __syncthreads();
    if (lane == 0) {
#pragma unroll
        for (int r = 0; r < 4; ++r) {
            int t = tb + r * 4 + wave;
            list[e1a[r] * T_TOKENS + base[e1a[r]] + s1a[r]] = t * 2 + 0;
            list[e2a[r] * T_TOKENS + base[e2a[r]] + s2a[r]] = t * 2 + 1;
        }
    }
}

// ---------------------------------------------------------------- compact
__global__ void k_compact(const int* __restrict__ counts, const int* __restrict__ list,
                          int* __restrict__ clist, int* __restrict__ rowOf) {
    int e = blockIdx.y;
    int s = blockIdx.x * 256 + threadIdx.x;
    int off = 0, cnt = 0;
#pragma unroll
    for (int ee = 0; ee < E_NUM; ++ee) {
        int c = counts[ee];
        int pc = (c + BM - 1) / BM * BM;
        if (ee < e) off += pc;
        if (ee == e) cnt = c;
    }
    int pcnt = (cnt + BM - 1) / BM * BM;
    if (s >= pcnt) return;
    int g = off + s;
    if (s < cnt) {
        int v = list[e * T_TOKENS + s];
        clist[g] = v >> 1;
        rowOf[v] = g;                 // v = tok*2 + slot
    } else {
        clist[g] = 0;                 // padding row gathers token 0 (output unused)
    }
}

// ---------------------------------------------------------------- up GEMM
// 128x256 tile, 512 threads (8 waves, 2m x 4n), rb-outer / nb-inner per XCD chunk
__global__ __launch_bounds__(512) void k_up_gemm(
        const ushort_t* __restrict__ xb, const ushort_t* __restrict__ wupT,
        const float* __restrict__ b_up, const int* __restrict__ counts,
        const int* __restrict__ clist, ushort_t* __restrict__ h) {
    int wg = blockIdx.x;
    int lin = (wg & 7) * (UP_BLOCKS / 8) + (wg >> 3);
    int nb = lin % NBU;                 // 0..11 (N-block of 256)
    int rb = lin / NBU;
    int total;
    int e = rb_expert(counts, rb, total);
    if (rb >= total) return;
    __shared__ __align__(16) ushort_t As[2][BM][BK];     // 8KB/buf
    __shared__ __align__(16) ushort_t Bs[2][256][BK];    // 16KB/buf
    int t = threadIdx.x, wave = t >> 6, lane = t & 63;
    int wm = wave >> 2, wn = wave & 3;  // 2m x 4n

    int row0 = rb * BM;
    int tokA = clist[row0 + (t >> 2)];          // rows 0..127 (t<512)
    const ushort_t* wb = wupT + (size_t)e * F_DIM * D_DIM + (size_t)(nb * 256) * D_DIM;

    float4v acc[4][4];
#pragma unroll
    for (int i = 0; i < 4; ++i)
#pragma unroll
        for (int j = 0; j < 4; ++j)
#pragma unroll
            for (int q = 0; q < 4; ++q) acc[i][j][q] = 0.f;

    int csw = (((t & 3) ^ ((t >> 3) & 3))) * 8;    // staged src chunk (swizzled)
    int swoff = (((lane >> 4) ^ (((lane & 15) >> 1) & 3))) * 8;  // read-side

    const ushort_t* gA  = xb + (size_t)tokA * D_DIM + csw;
    const ushort_t* gB0 = wb + (size_t)(t >> 2) * D_DIM + csw;          // rows 0..127
    const ushort_t* gB1 = wb + (size_t)(128 + (t >> 2)) * D_DIM + csw;  // rows 128..255

#define STAGE_UP(buf, kt) do { int k0 = (kt) * BK;                            \
        char* AsB = (char*)&As[buf][0][0]; char* BsB = (char*)&Bs[buf][0][0]; \
        GLOAD_LDS16(gA + k0, AsB + wave * 1024);                              \
        GLOAD_LDS16(gB0 + k0, BsB + wave * 1024);                             \
        GLOAD_LDS16(gB1 + k0, BsB + 8192 + wave * 1024); } while (0)

    STAGE_UP(0, 0);
    __syncthreads();
    const int nt = D_DIM / BK;          // 24
    for (int kt = 0; kt < nt; ++kt) {
        int buf = kt & 1;
        if (kt + 1 < nt) STAGE_UP(buf ^ 1, kt + 1);
        short8 af[4], bfr[4];
#pragma unroll
        for (int m = 0; m < 4; ++m)
            af[m] = *(const short8*)&As[buf][wm * 64 + m * 16 + (lane & 15)][swoff];
#pragma unroll
        for (int n = 0; n < 4; ++n)
            bfr[n] = *(const short8*)&Bs[buf][wn * 64 + n * 16 + (lane & 15)][swoff];
#pragma unroll
        for (int m = 0; m < 4; ++m)
#pragma unroll
            for (int n = 0; n < 4; ++n)
                acc[m][n] = __builtin_amdgcn_mfma_f32_16x16x32_bf16(af[m], bfr[n], acc[m][n], 0, 0, 0);
        __syncthreads();
    }

#pragma unroll
    for (int m = 0; m < 4; ++m) {
        int row_local = wm * 64 + m * 16 + (lane >> 4) * 4;
#pragma unroll
        for (int n = 0; n < 4; ++n) {
            int col = nb * 256 + wn * 64 + n * 16 + (lane & 15);
            float bia = b_up[e * F_DIM + col];
#pragma unroll
            for (int j = 0; j < 4; ++j) {
                float v = acc[m][n][j] + bia;
                h[(size_t)(row0 + row_local + j) * F_DIM + col] = f2bf(gelu_fast(v));
            }
        }
    }
}

// ---------------------------------------------------------------- down GEMM
// 128x128 tile, BK=32, split-K x2, bf16 partial planes (r12 config)
__global__ void k_down_gemm(const ushort_t* __restrict__ h, const ushort_t* __restrict__ wdT,
                            const float* __restrict__ b_down, const int* __restrict__ counts,
                            ushort_t* __restrict__ yb) {
    int wg = blockIdx.x;
    int lin = (wg & 7) * (DN_BLOCKS / 8) + (wg >> 3);
    int nbkc = lin % (NBD * 2);        // 0..11 inner
    int rb = lin / (NBD * 2);          // rb outer: A tile hot in L2 per XCD
    int nb = nbkc >> 1, kc = nbkc & 1;
    int total;
    int e = rb_expert(counts, rb, total);
    if (rb >= total) return;
    __shared__ __align__(16) ushort_t As[2][BM][BK];
    __shared__ __align__(16) ushort_t Bs[2][BM][BK];
    int t = threadIdx.x, wave = t >> 6, lane = t & 63;
    int wm = wave >> 1, wn = wave & 1;

    int row0 = rb * BM;
    int kbase = kc * KHALF;
    const ushort_t* ha = h + (size_t)row0 * F_DIM + kbase;
    const ushort_t* wb = wdT + (size_t)e * D_DIM * F_DIM + (size_t)(nb * BM) * F_DIM + kbase;

    float4v acc[4][4];
#pragma unroll
    for (int i = 0; i < 4; ++i)
#pragma unroll
        for (int j = 0; j < 4; ++j)
#pragma unroll
            for (int q = 0; q < 4; ++q) acc[i][j][q] = 0.f;

    int csw = (((t & 3) ^ ((t >> 3) & 3))) * 8;
    int swoff = (((lane >> 4) ^ (((lane & 15) >> 1) & 3))) * 8;

    const ushort_t* gA0 = ha + (size_t)(t >> 2) * F_DIM + csw;
    const ushort_t* gA1 = ha + (size_t)(64 + (t >> 2)) * F_DIM + csw;
    const ushort_t* gB0 = wb + (size_t)(t >> 2) * F_DIM + csw;
    const ushort_t* gB1 = wb + (size_t)(64 + (t >> 2)) * F_DIM + csw;

#define STAGE_DN(buf, kt) do { int k0 = (kt) * BK;                            \
        char* AsB = (char*)&As[buf][0][0]; char* BsB = (char*)&Bs[buf][0][0]; \
        GLOAD_LDS16(gA0 + k0, AsB + wave * 1024);                             \
        GLOAD_LDS16(gA1 + k0, AsB + 4096 + wave * 1024);                      \
        GLOAD_LDS16(gB0 + k0, BsB + wave * 1024);                             \
        GLOAD_LDS16(gB1 + k0, BsB + 4096 + wave * 1024); } while (0)

    STAGE_DN(0, 0);
    __syncthreads();
    const int nt = KHALF / BK;
    for (int kt = 0; kt < nt; ++kt) {
        int buf = kt & 1;
        if (kt + 1 < nt) STAGE_DN(buf ^ 1, kt + 1);
        short8 af[4], bfr[4];
#pragma unroll
        for (int m = 0; m < 4; ++m)
            af[m] = *(const short8*)&As[buf][wm * 64 + m * 16 + (lane & 15)][swoff];
#pragma unroll
        for (int n = 0; n < 4; ++n)
            bfr[n] = *(const short8*)&Bs[buf][wn * 64 + n * 16 + (lane & 15)][swoff];
#pragma unroll
        for (int m = 0; m < 4; ++m)
#pragma unroll
            for (int n = 0; n < 4; ++n)
                acc[m][n] = __builtin_amdgcn_mfma_f32_16x16x32_bf16(af[m], bfr[n], acc[m][n], 0, 0, 0);
        __syncthreads();
    }

    ushort_t* ybk = yb + (size_t)kc * GROWS * D_DIM;
#pragma unroll
    for (int m = 0; m < 4; ++m) {
        int row_local = wm * 64 + m * 16 + (lane >> 4) * 4;
#pragma unroll
        for (int n = 0; n < 4; ++n) {
            int col = nb * BM + wn * 64 + n * 16 + (lane & 15);
            float bia = (kc == 0) ? b_down[e * D_DIM + col] : 0.f;
#pragma unroll
            for (int j = 0; j < 4; ++j) {
                ybk[(size_t)(row0 + row_local + j) * D_DIM + col] =
                    f2bf(acc[m][n][j] + bia);
            }
        }
    }
}

// ---------------------------------------------------------------- combine
// out[t] = w0*(y[0][g0]+y[1][g0]) + w1*(y[0][g1]+y[1][g1])
__global__ void k_combine(const ushort_t* __restrict__ yb, const int* __restrict__ rowOf,
                          const float* __restrict__ wsel, float* __restrict__ out) {
    int wave = threadIdx.x >> 6, lane = threadIdx.x & 63;
    int t = blockIdx.x * 4 + wave;
    int g0 = rowOf[t * 2], g1 = rowOf[t * 2 + 1];
    float w0 = wsel[t * 2], w1 = wsel[t * 2 + 1];
    const ushort_t* a0 = yb + (size_t)g0 * D_DIM;
    const ushort_t* a1 = yb + ((size_t)GROWS + g0) * D_DIM;
    const ushort_t* b0 = yb + (size_t)g1 * D_DIM;
    const ushort_t* b1 = yb + ((size_t)GROWS + g1) * D_DIM;
    float4v* o = (float4v*)(out + (size_t)t * D_DIM);
#pragma unroll
    for (int i = 0; i < 3; ++i) {
        int idx = (lane + i * 64) * 4;
        short4v va0 = *(const short4v*)&a0[idx];
        short4v va1 = *(const short4v*)&a1[idx];
        short4v vb0 = *(const short4v*)&b0[idx];
        short4v vb1 = *(const short4v*)&b1[idx];
        float4v r;
#pragma unroll
        for (int q = 0; q < 4; ++q)
            r[q] = w0 * (bf2f((ushort_t)va0[q]) + bf2f((ushort_t)va1[q]))
                 + w1 * (bf2f((ushort_t)vb0[q]) + bf2f((ushort_t)vb1[q]));
        o[(lane + i * 64)] = r;
    }
}

// ---------------------------------------------------------------- launch
extern "C" void kernel_launch(void* const* d_in, const int* in_sizes, int n_in,
                              void* d_out, int out_size, void* d_ws, size_t ws_size,
                              hipStream_t stream) {
    const float* x   = (const float*)d_in[0];   // [2,2048,768]
    const float* gw  = (const float*)d_in[1];   // [768,8]
    const float* wup = (const float*)d_in[2];   // [8,768,3072]
    const float* bup = (const float*)d_in[3];   // [8,3072]
    const float* wdn = (const float*)d_in[4];   // [8,3072,768]
    const float* bdn = (const float*)d_in[5];   // [8,768]
    float* out = (float*)d_out;

    char* ws = (char*)d_ws;
    int*   counts = (int*)(ws);
    int*   list   = (int*)(ws + 1024);
    size_t p = 1024 + (size_t)E_NUM * T_TOKENS * 4;
    int*   clist  = (int*)(ws + p); p += (size_t)GROWS * 4;
    int*   rowOf  = (int*)(ws + p); p += (size_t)T_TOKENS * 2 * 4;
    float* wsel   = (float*)(ws + p); p += (size_t)T_TOKENS * 2 * 4;
    p = (p + 255) & ~(size_t)255;
    size_t p_xb = p;
    ushort_t* xb   = (ushort_t*)(ws + p); p += (size_t)T_TOKENS * D_DIM * 2;
    ushort_t* wupT = (ushort_t*)(ws + p); p += (size_t)E_NUM * D_DIM * F_DIM * 2;
    ushort_t* wdnT = (ushort_t*)(ws + p); p += (size_t)E_NUM * D_DIM * F_DIM * 2;
    ushort_t* hbuf = (ushort_t*)(ws + p); p += (size_t)GROWS * F_DIM * 2;
    // ybuf (2 planes bf16, 28.3MB) aliases xb+wupT (44MB, dead after up GEMM)
    ushort_t* ybuf = (ushort_t*)(ws + p_xb);

    hipMemsetAsync(counts, 0, E_NUM * sizeof(int), stream);
    k_prep<<<PREP_TOTAL, 256, 0, stream>>>(x, gw, wup, wdn, counts, list, wsel,
                                           xb, wupT, wdnT);
    k_compact<<<dim3(17, E_NUM), 256, 0, stream>>>(counts, list, clist, rowOf);
    k_up_gemm<<<UP_BLOCKS, 512, 0, stream>>>(xb, wupT, bup, counts, clist, hbuf);
    k_down_gemm<<<DN_BLOCKS, 256, 0, stream>>>(hbuf, wdnT, bdn, counts, ybuf);
    k_combine<<<T_TOKENS / 4, 256, 0, stream>>>(ybuf, rowOf, wsel, out);
}

// Round 17
// 203.528 us; speedup vs baseline: 1.0248x; 1.0248x over previous
//
#include <hip/hip_runtime.h>
#include <hip/hip_bf16.h>
#include <math.h>

// Problem constants (B=2,S=2048 -> T=4096 tokens)
#define T_TOKENS 4096
#define D_DIM 768
#define F_DIM 3072
#define E_NUM 8

#define BM 128
#define BK 32
#define RBMAX 72                 // max padded 128-row blocks
#define NBU (F_DIM / 256)        // 12 N-blocks of 256 for up
#define NBD (D_DIM / 128)        // 6 N-blocks of 128 for down
#define UP_BLOCKS (NBU * RBMAX)  // 864
#define KHALF (F_DIM / 2)        // 1536: down split-K chunk
#define DN_BLOCKS (NBD * RBMAX * 2)  // 864 (rb outer x (nb,kc) inner)
#define GROWS (RBMAX * BM)       // 9216 padded rows

#define TILE_LDS (64 * 66)       // bf16 elems per wave-private transpose tile
#define TRT_WUP 4608             // 64x64 tiles in wup
#define TRT_TOT 9216             // + wdn

typedef __attribute__((ext_vector_type(8))) short short8;
typedef __attribute__((ext_vector_type(4))) short short4v;
typedef __attribute__((ext_vector_type(4))) float float4v;
typedef unsigned short ushort_t;
typedef unsigned long long ull_t;

__device__ __forceinline__ ushort_t f2bf(float f) {
    union { float f; unsigned u; } v; v.f = f;
    unsigned r = v.u + 0x7fffu + ((v.u >> 16) & 1u);   // RNE
    return (ushort_t)(r >> 16);
}

__device__ __forceinline__ float bf2f(ushort_t u) {
    union { unsigned u; float f; } v; v.u = ((unsigned)u) << 16;
    return v.f;
}

__device__ __forceinline__ float gelu_fast(float v) {
    float u = v + 0.044715f * v * v * v;
    return v / (1.f + __expf(-1.5957691216f * u));
}

#define GLOAD_LDS16(gp, lp) __builtin_amdgcn_global_load_lds( \
    (const __attribute__((address_space(1))) void*)(gp),      \
    (__attribute__((address_space(3))) void*)(lp), 16, 0, 0)

// expert for padded 128-row block rb, plus total block count
__device__ __forceinline__ int rb_expert(const int* __restrict__ counts,
                                         int rb, int& total) {
    int e = 0, acc = 0;
#pragma unroll
    for (int ee = 0; ee < E_NUM; ++ee) {
        int nbe = (counts[ee] + BM - 1) / BM;
        if (rb >= acc && rb < acc + nbe) e = ee;
        acc += nbe;
    }
    total = acc;
    return e;
}

// ---------------------------------------------------------------- tile coords
__device__ __forceinline__ void tile_coords(int g, int R, int C,
                                            int& e, int& r0, int& c0) {
    int tpr = C / 64, tpc = R / 64;
    e = g / (tpr * tpc);
    int rem = g % (tpr * tpc);
    r0 = (rem / tpr) * 64;
    c0 = (rem % tpr) * 64;
}

// ------------------------------------------------- per-WAVE barrier-free transpose
__device__ __forceinline__ void wave_transpose64(const float* __restrict__ ip,
                                                 ushort_t* __restrict__ op,
                                                 int R, int C, int r0, int c0,
                                                 ushort_t* __restrict__ tl) {
    int l = threadIdx.x & 63;
    int lr = l >> 4;             // 0..3
    int lc4 = (l & 15) * 4;      // 0,4,...,60

    float4v v[16];
#pragma unroll
    for (int i = 0; i < 16; ++i)
        v[i] = *(const float4v*)&ip[(size_t)(r0 + 4 * i + lr) * C + c0 + lc4];
#pragma unroll
    for (int i = 0; i < 16; ++i) {
        short4v s = { (short)f2bf(v[i][0]), (short)f2bf(v[i][1]),
                      (short)f2bf(v[i][2]), (short)f2bf(v[i][3]) };
        *(short4v*)&tl[(4 * i + lr) * 66 + lc4] = s;
    }
    asm volatile("s_waitcnt lgkmcnt(0)" ::: "memory");
#pragma unroll
    for (int i = 0; i < 16; ++i) {
        int rr = 4 * i + lr;                     // output row (= orig col c0+rr)
        short4v s = { (short)tl[(lc4 + 0) * 66 + rr],
                      (short)tl[(lc4 + 1) * 66 + rr],
                      (short)tl[(lc4 + 2) * 66 + rr],
                      (short)tl[(lc4 + 3) * 66 + rr] };
        *(short4v*)&op[(size_t)(c0 + rr) * R + r0 + lc4] = s;
    }
}

// ---------------------------------------------------------------- transpose kernel
__global__ __launch_bounds__(256) void k_trans(const float* __restrict__ wup,
                                               const float* __restrict__ wdn,
                                               ushort_t* __restrict__ wupT,
                                               ushort_t* __restrict__ wdnT) {
    __shared__ ushort_t ttile[4][TILE_LDS];
    int wave = threadIdx.x >> 6;
    int g = blockIdx.x * 4 + wave;               // 0..9215
    const float* in; ushort_t* outp; int R, C;
    if (g < TRT_WUP) { in = wup; outp = wupT; R = D_DIM; C = F_DIM; }
    else { g -= TRT_WUP; in = wdn; outp = wdnT; R = F_DIM; C = D_DIM; }
    int e, r0, c0;
    tile_coords(g, R, C, e, r0, c0);
    wave_transpose64(in + (size_t)e * R * C, outp + (size_t)e * R * C,
                     R, C, r0, c0, &ttile[wave][0]);
}

// ---------------------------------------------------------------- gate (+ x->bf16)
__global__ __launch_bounds__(1024) void k_gate(const float* __restrict__ x,
                                               const float* __restrict__ gw,
                                               int* __restrict__ counts,
                                               int* __restrict__ list,
                                               float* __restrict__ wsel,
                                               ushort_t* __restrict__ xb) {
    __shared__ int hist[E_NUM];
    __shared__ int base[E_NUM];
    int wave = threadIdx.x >> 6, lane = threadIdx.x & 63;
    int t = blockIdx.x * 16 + wave;

    float acc[E_NUM];
#pragma unroll
    for (int e = 0; e < E_NUM; ++e) acc[e] = 0.f;
    const float4v* xr4 = (const float4v*)(x + (size_t)t * D_DIM);
    ull_t* xbr = (ull_t*)(xb + (size_t)t * D_DIM);
#pragma unroll
    for (int i = 0; i < 3; ++i) {
        int j = lane + i * 64;                   // float4 index within row
        float4v v = xr4[j];
        xbr[j] = (ull_t)f2bf(v[0]) | ((ull_t)f2bf(v[1]) << 16) |
                 ((ull_t)f2bf(v[2]) << 32) | ((ull_t)f2bf(v[3]) << 48);
        int d0 = 4 * j;
#pragma unroll
        for (int q = 0; q < 4; ++q) {
            const float* g = gw + (size_t)(d0 + q) * E_NUM;
#pragma unroll
            for (int e = 0; e < E_NUM; ++e) acc[e] += v[q] * g[e];
        }
    }
#pragma unroll
    for (int e = 0; e < E_NUM; ++e) {
#pragma unroll
        for (int s = 32; s >= 1; s >>= 1) acc[e] += __shfl_xor(acc[e], s);
    }

    if (threadIdx.x < E_NUM) hist[threadIdx.x] = 0;
    __syncthreads();

    int e1 = 0, e2 = 0, s1 = 0, s2 = 0;
    if (lane == 0) {
        float mx = acc[0];
#pragma unroll
        for (int e = 1; e < E_NUM; ++e) mx = fmaxf(mx, acc[e]);
        float p[E_NUM], sum = 0.f;
#pragma unroll
        for (int e = 0; e < E_NUM; ++e) { p[e] = expf(acc[e] - mx); sum += p[e]; }
        float inv = 1.f / sum;
#pragma unroll
        for (int e = 0; e < E_NUM; ++e) p[e] *= inv;
#pragma unroll
        for (int e = 1; e < E_NUM; ++e) if (p[e] > p[e1]) e1 = e;
        e2 = (e1 == 0) ? 1 : 0;
#pragma unroll
        for (int e = 0; e < E_NUM; ++e) if (e != e1 && p[e] > p[e2]) e2 = e;
        s1 = atomicAdd(&hist[e1], 1);            // LDS atomic
        s2 = atomicAdd(&hist[e2], 1);
        wsel[t * 2 + 0] = p[e1];
        wsel[t * 2 + 1] = p[e2];
    }
    __syncthreads();
    if (threadIdx.x < E_NUM)
        base[threadIdx.x] = atomicAdd(&counts[threadIdx.x], hist[threadIdx.x]);
    __syncthreads();
    if (lane == 0) {
        list[e1 * T_TOKENS + base[e1] + s1] = t * 2 + 0;   // token | slot bit
        list[e2 * T_TOKENS + base[e2] + s2] = t * 2 + 1;
    }
}

// ---------------------------------------------------------------- compact
__global__ void k_compact(const int* __restrict__ counts, const int* __restrict__ list,
                          int* __restrict__ clist, int* __restrict__ rowOf) {
    int e = blockIdx.y;
    int s = blockIdx.x * 256 + threadIdx.x;
    int off = 0, cnt = 0;
#pragma unroll
    for (int ee = 0; ee < E_NUM; ++ee) {
        int c = counts[ee];
        int pc = (c + BM - 1) / BM * BM;
        if (ee < e) off += pc;
        if (ee == e) cnt = c;
    }
    int pcnt = (cnt + BM - 1) / BM * BM;
    if (s >= pcnt) return;
    int g = off + s;
    if (s < cnt) {
        int v = list[e * T_TOKENS + s];
        clist[g] = v >> 1;
        rowOf[v] = g;                 // v = tok*2 + slot
    } else {
        clist[g] = 0;                 // padding row gathers token 0 (output unused)
    }
}

// ---------------------------------------------------------------- up GEMM
// 128x256 tile, 512 threads (8 waves, 2m x 4n), rb-outer / nb-inner per XCD chunk
__global__ __launch_bounds__(512) void k_up_gemm(
        const ushort_t* __restrict__ xb, const ushort_t* __restrict__ wupT,
        const float* __restrict__ b_up, const int* __restrict__ counts,
        const int* __restrict__ clist, ushort_t* __restrict__ h) {
    int wg = blockIdx.x;
    int lin = (wg & 7) * (UP_BLOCKS / 8) + (wg >> 3);
    int nb = lin % NBU;                 // 0..11 (N-block of 256)
    int rb = lin / NBU;
    int total;
    int e = rb_expert(counts, rb, total);
    if (rb >= total) return;
    __shared__ __align__(16) ushort_t As[2][BM][BK];     // 8KB/buf
    __shared__ __align__(16) ushort_t Bs[2][256][BK];    // 16KB/buf
    int t = threadIdx.x, wave = t >> 6, lane = t & 63;
    int wm = wave >> 2, wn = wave & 3;  // 2m x 4n

    int row0 = rb * BM;
    int tokA = clist[row0 + (t >> 2)];          // rows 0..127 (t<512)
    const ushort_t* wb = wupT + (size_t)e * F_DIM * D_DIM + (size_t)(nb * 256) * D_DIM;

    float4v acc[4][4];
#pragma unroll
    for (int i = 0; i < 4; ++i)
#pragma unroll
        for (int j = 0; j < 4; ++j)
#pragma unroll
            for (int q = 0; q < 4; ++q) acc[i][j][q] = 0.f;

    int csw = (((t & 3) ^ ((t >> 3) & 3))) * 8;    // staged src chunk (swizzled)
    int swoff = (((lane >> 4) ^ (((lane & 15) >> 1) & 3))) * 8;  // read-side

    const ushort_t* gA  = xb + (size_t)tokA * D_DIM + csw;
    const ushort_t* gB0 = wb + (size_t)(t >> 2) * D_DIM + csw;          // rows 0..127
    const ushort_t* gB1 = wb + (size_t)(128 + (t >> 2)) * D_DIM + csw;  // rows 128..255

#define STAGE_UP(buf, kt) do { int k0 = (kt) * BK;                            \
        char* AsB = (char*)&As[buf][0][0]; char* BsB = (char*)&Bs[buf][0][0]; \
        GLOAD_LDS16(gA + k0, AsB + wave * 1024);                              \
        GLOAD_LDS16(gB0 + k0, BsB + wave * 1024);                             \
        GLOAD_LDS16(gB1 + k0, BsB + 8192 + wave * 1024); } while (0)

    STAGE_UP(0, 0);
    __syncthreads();
    const int nt = D_DIM / BK;          // 24
    for (int kt = 0; kt < nt; ++kt) {
        int buf = kt & 1;
        if (kt + 1 < nt) STAGE_UP(buf ^ 1, kt + 1);
        short8 af[4], bfr[4];
#pragma unroll
        for (int m = 0; m < 4; ++m)
            af[m] = *(const short8*)&As[buf][wm * 64 + m * 16 + (lane & 15)][swoff];
#pragma unroll
        for (int n = 0; n < 4; ++n)
            bfr[n] = *(const short8*)&Bs[buf][wn * 64 + n * 16 + (lane & 15)][swoff];
#pragma unroll
        for (int m = 0; m < 4; ++m)
#pragma unroll
            for (int n = 0; n < 4; ++n)
                acc[m][n] = __builtin_amdgcn_mfma_f32_16x16x32_bf16(af[m], bfr[n], acc[m][n], 0, 0, 0);
        __syncthreads();
    }

#pragma unroll
    for (int m = 0; m < 4; ++m) {
        int row_local = wm * 64 + m * 16 + (lane >> 4) * 4;
#pragma unroll
        for (int n = 0; n < 4; ++n) {
            int col = nb * 256 + wn * 64 + n * 16 + (lane & 15);
            float bia = b_up[e * F_DIM + col];
#pragma unroll
            for (int j = 0; j < 4; ++j) {
                float v = acc[m][n][j] + bia;
                h[(size_t)(row0 + row_local + j) * F_DIM + col] = f2bf(gelu_fast(v));
            }
        }
    }
}

// ---------------------------------------------------------------- down GEMM
// 128x128 tile, BK=32, split-K x2, bf16 partial planes, rb-outer per XCD chunk
__global__ void k_down_gemm(const ushort_t* __restrict__ h, const ushort_t* __restrict__ wdT,
                            const float* __restrict__ b_down, const int* __restrict__ counts,
                            ushort_t* __restrict__ yb) {
    int wg = blockIdx.x;
    int lin = (wg & 7) * (DN_BLOCKS / 8) + (wg >> 3);
    int nbkc = lin % (NBD * 2);        // 0..11 inner
    int rb = lin / (NBD * 2);          // rb outer: A tile hot in L2 per XCD
    int nb = nbkc >> 1, kc = nbkc & 1;
    int total;
    int e = rb_expert(counts, rb, total);
    if (rb >= total) return;
    __shared__ __align__(16) ushort_t As[2][BM][BK];
    __shared__ __align__(16) ushort_t Bs[2][BM][BK];
    int t = threadIdx.x, wave = t >> 6, lane = t & 63;
    int wm = wave >> 1, wn = wave & 1;

    int row0 = rb * BM;
    int kbase = kc * KHALF;
    const ushort_t* ha = h + (size_t)row0 * F_DIM + kbase;
    const ushort_t* wb = wdT + (size_t)e * D_DIM * F_DIM + (size_t)(nb * BM) * F_DIM + kbase;

    float4v acc[4][4];
#pragma unroll
    for (int i = 0; i < 4; ++i)
#pragma unroll
        for (int j = 0; j < 4; ++j)
#pragma unroll
            for (int q = 0; q < 4; ++q) acc[i][j][q] = 0.f;

    int csw = (((t & 3) ^ ((t >> 3) & 3))) * 8;
    int swoff = (((lane >> 4) ^ (((lane & 15) >> 1) & 3))) * 8;

    const ushort_t* gA0 = ha + (size_t)(t >> 2) * F_DIM + csw;
    const ushort_t* gA1 = ha + (size_t)(64 + (t >> 2)) * F_DIM + csw;
    const ushort_t* gB0 = wb + (size_t)(t >> 2) * F_DIM + csw;
    const ushort_t* gB1 = wb + (size_t)(64 + (t >> 2)) * F_DIM + csw;

#define STAGE_DN(buf, kt) do { int k0 = (kt) * BK;                            \
        char* AsB = (char*)&As[buf][0][0]; char* BsB = (char*)&Bs[buf][0][0]; \
        GLOAD_LDS16(gA0 + k0, AsB + wave * 1024);                             \
        GLOAD_LDS16(gA1 + k0, AsB + 4096 + wave * 1024);                      \
        GLOAD_LDS16(gB0 + k0, BsB + wave * 1024);                             \
        GLOAD_LDS16(gB1 + k0, BsB + 4096 + wave * 1024); } while (0)

    STAGE_DN(0, 0);
    __syncthreads();
    const int nt = KHALF / BK;
    for (int kt = 0; kt < nt; ++kt) {
        int buf = kt & 1;
        if (kt + 1 < nt) STAGE_DN(buf ^ 1, kt + 1);
        short8 af[4], bfr[4];
#pragma unroll
        for (int m = 0; m < 4; ++m)
            af[m] = *(const short8*)&As[buf][wm * 64 + m * 16 + (lane & 15)][swoff];
#pragma unroll
        for (int n = 0; n < 4; ++n)
            bfr[n] = *(const short8*)&Bs[buf][wn * 64 + n * 16 + (lane & 15)][swoff];
#pragma unroll
        for (int m = 0; m < 4; ++m)
#pragma unroll
            for (int n = 0; n < 4; ++n)
                acc[m][n] = __builtin_amdgcn_mfma_f32_16x16x32_bf16(af[m], bfr[n], acc[m][n], 0, 0, 0);
        __syncthreads();
    }

    ushort_t* ybk = yb + (size_t)kc * GROWS * D_DIM;
#pragma unroll
    for (int m = 0; m < 4; ++m) {
        int row_local = wm * 64 + m * 16 + (lane >> 4) * 4;
#pragma unroll
        for (int n = 0; n < 4; ++n) {
            int col = nb * BM + wn * 64 + n * 16 + (lane & 15);
            float bia = (kc == 0) ? b_down[e * D_DIM + col] : 0.f;
#pragma unroll
            for (int j = 0; j < 4; ++j) {
                ybk[(size_t)(row0 + row_local + j) * D_DIM + col] =
                    f2bf(acc[m][n][j] + bia);
            }
        }
    }
}

// ---------------------------------------------------------------- combine
// out[t] = w0*(y[0][g0]+y[1][g0]) + w1*(y[0][g1]+y[1][g1])
__global__ void k_combine(const ushort_t* __restrict__ yb, const int* __restrict__ rowOf,
                          const float* __restrict__ wsel, float* __restrict__ out) {
    int wave = threadIdx.x >> 6, lane = threadIdx.x & 63;
    int t = blockIdx.x * 4 + wave;
    int g0 = rowOf[t * 2], g1 = rowOf[t * 2 + 1];
    float w0 = wsel[t * 2], w1 = wsel[t * 2 + 1];
    const ushort_t* a0 = yb + (size_t)g0 * D_DIM;
    const ushort_t* a1 = yb + ((size_t)GROWS + g0) * D_DIM;
    const ushort_t* b0 = yb + (size_t)g1 * D_DIM;
    const ushort_t* b1 = yb + ((size_t)GROWS + g1) * D_DIM;
    float4v* o = (float4v*)(out + (size_t)t * D_DIM);
#pragma unroll
    for (int i = 0; i < 3; ++i) {
        int idx = (lane + i * 64) * 4;
        short4v va0 = *(const short4v*)&a0[idx];
        short4v va1 = *(const short4v*)&a1[idx];
        short4v vb0 = *(const short4v*)&b0[idx];
        short4v vb1 = *(const short4v*)&b1[idx];
        float4v r;
#pragma unroll
        for (int q = 0; q < 4; ++q)
            r[q] = w0 * (bf2f((ushort_t)va0[q]) + bf2f((ushort_t)va1[q]))
                 + w1 * (bf2f((ushort_t)vb0[q]) + bf2f((ushort_t)vb1[q]));
        o[(lane + i * 64)] = r;
    }
}

// ---------------------------------------------------------------- launch
extern "C" void kernel_launch(void* const* d_in, const int* in_sizes, int n_in,
                              void* d_out, int out_size, void* d_ws, size_t ws_size,
                              hipStream_t stream) {
    const float* x   = (const float*)d_in[0];   // [2,2048,768]
    const float* gw  = (const float*)d_in[1];   // [768,8]
    const float* wup = (const float*)d_in[2];   // [8,768,3072]
    const float* bup = (const float*)d_in[3];   // [8,3072]
    const float* wdn = (const float*)d_in[4];   // [8,3072,768]
    const float* bdn = (const float*)d_in[5];   // [8,768]
    float* out = (float*)d_out;

    char* ws = (char*)d_ws;
    int*   counts = (int*)(ws);
    int*   list   = (int*)(ws + 1024);
    size_t p = 1024 + (size_t)E_NUM * T_TOKENS * 4;
    int*   clist  = (int*)(ws + p); p += (size_t)GROWS * 4;
    int*   rowOf  = (int*)(ws + p); p += (size_t)T_TOKENS * 2 * 4;
    float* wsel   = (float*)(ws + p); p += (size_t)T_TOKENS * 2 * 4;
    p = (p + 255) & ~(size_t)255;
    size_t p_xb = p;
    ushort_t* xb   = (ushort_t*)(ws + p); p += (size_t)T_TOKENS * D_DIM * 2;
    ushort_t* wupT = (ushort_t*)(ws + p); p += (size_t)E_NUM * D_DIM * F_DIM * 2;
    ushort_t* wdnT = (ushort_t*)(ws + p); p += (size_t)E_NUM * D_DIM * F_DIM * 2;
    ushort_t* hbuf = (ushort_t*)(ws + p); p += (size_t)GROWS * F_DIM * 2;
    // ybuf (2 planes bf16, 28.3MB) aliases xb+wupT (44MB, dead after up GEMM)
    ushort_t* ybuf = (ushort_t*)(ws + p_xb);

    hipMemsetAsync(counts, 0, E_NUM * sizeof(int), stream);
    k_gate<<<T_TOKENS / 16, 1024, 0, stream>>>(x, gw, counts, list, wsel, xb);
    k_trans<<<TRT_TOT / 4, 256, 0, stream>>>(wup, wdn, wupT, wdnT);
    k_compact<<<dim3(17, E_NUM), 256, 0, stream>>>(counts, list, clist, rowOf);
    k_up_gemm<<<UP_BLOCKS, 512, 0, stream>>>(xb, wupT, bup, counts, clist, hbuf);
    k_down_gemm<<<DN_BLOCKS, 256, 0, stream>>>(hbuf, wdnT, bdn, counts, ybuf);
    k_combine<<<T_TOKENS / 4, 256, 0, stream>>>(ybuf, rowOf, wsel, out);
}